// Round 8
// baseline (468.248 us; speedup 1.0000x reference)
//
#include <hip/hip_runtime.h>

// ---------------------------------------------------------------------------
// Transformer block, bf16-resident: LN1 -> QKV(+V-transpose) -> flash-MHA ->
// proj(+x) -> LN2 -> GELU-MLP(+x2).  B=4,N=2048,D=768,H=12,d=64,HID=3072.
// fp32 in/out; bf16 activations/weights; fp32 accum/softmax/residuals.
// GEMM: two BK=32 panels per barrier-pair (half the barrier drains).
// Attention: S^T=K*Q^T, O^T=V^T*P, shift-free softmax, K/V reg-prefetch.
// ---------------------------------------------------------------------------

#define DIM    768
#define NHEAD  12
#define HDIM   64
#define HID    3072
#define BATCH  4
#define SEQ    2048
#define MTOT   (BATCH * SEQ)      // 8192
#define D3     (3 * DIM)          // 2304

// 1/sqrt(64) * log2(e): folded into Q so softmax uses raw v_exp_f32 (2^x)
#define QSCALE 0.18033688011112042f
// 2*log2(e)*sqrt(2/pi) for exp2-based tanh-GELU
#define GELU_K 2.30220816f

typedef short bf16x8 __attribute__((ext_vector_type(8)));   // 4 VGPRs
typedef float f32x4  __attribute__((ext_vector_type(4)));

__device__ __forceinline__ float exp2fast(float x) {
    return __builtin_amdgcn_exp2f(x);      // v_exp_f32: 2^x
}

__device__ __forceinline__ float gelu_f(float v) {
    float y = v * (1.f + 0.044715f * v * v) * GELU_K;
    float t = exp2fast(fminf(y, 30.f));    // clamp: avoid inf/inf
#if __has_builtin(__builtin_amdgcn_rcpf)
    return v * t * __builtin_amdgcn_rcpf(t + 1.f);
#else
    return v * t / (t + 1.f);
#endif
}

__device__ __forceinline__ short f2bf(float f) {
    union { float f; unsigned u; } c; c.f = f;
    unsigned r = c.u + 0x7FFFu + ((c.u >> 16) & 1u);   // RNE
    return (short)(r >> 16);
}

// pack 4 fp32 -> 4 bf16 (hw pk-cvt when available)
__device__ __forceinline__ short4 pk4bf(float a, float b, float c, float d) {
#if __has_builtin(__builtin_amdgcn_cvt_pk_bf16_f32)
    auto lo = __builtin_amdgcn_cvt_pk_bf16_f32(a, b);
    auto hi = __builtin_amdgcn_cvt_pk_bf16_f32(c, d);
    union { decltype(lo) v; int i; } ul, uh;
    ul.v = lo; uh.v = hi;
    short4 r;
    *(int*)&r.x = ul.i; *(int*)&r.z = uh.i;
    return r;
#else
    return make_short4(f2bf(a), f2bf(b), f2bf(c), f2bf(d));
#endif
}

// async global->LDS, 16B per lane (wave-uniform LDS base, lane-scatter i*16)
__device__ __forceinline__ void gld_lds16(const short* g, short* l) {
    __builtin_amdgcn_global_load_lds(
        (const __attribute__((address_space(1))) unsigned int*)g,
        (__attribute__((address_space(3))) unsigned int*)l, 16, 0, 0);
}

// ---------------------------------------------------------------------------
// fp32 -> bf16 bulk convert, 4 weight tensors fused into one launch.
// ---------------------------------------------------------------------------
__global__ __launch_bounds__(256) void tobf4_k(
    const float* __restrict__ s0, short* __restrict__ d0, int n0,
    const float* __restrict__ s1, short* __restrict__ d1, int n1,
    const float* __restrict__ s2, short* __restrict__ d2, int n2,
    const float* __restrict__ s3, short* __restrict__ d3, int n3)
{
    int i = blockIdx.x * 256 + threadIdx.x;   // index in float4 units
    const float* s; short* d;
    if (i < n0)                { s = s0; d = d0; }
    else if ((i -= n0) < n1)   { s = s1; d = d1; }
    else if ((i -= n1) < n2)   { s = s2; d = d2; }
    else if ((i -= n2) < n3)   { s = s3; d = d3; }
    else return;
    float4 v = ((const float4*)s)[i];
    ((short4*)d)[i] = pk4bf(v.x, v.y, v.z, v.w);
}

// ---------------------------------------------------------------------------
// LayerNorm, fp32 in -> bf16 out. One 256-thread block per row of 768.
// ---------------------------------------------------------------------------
__global__ __launch_bounds__(256) void ln_k(
    const float* __restrict__ x, const float* __restrict__ g,
    const float* __restrict__ bta, short* __restrict__ y)
{
    __shared__ float sb[2][4];
    const int row = blockIdx.x, tid = threadIdx.x;
    const float* xr = x + (size_t)row * DIM;
    float v0 = xr[tid], v1 = xr[tid + 256], v2 = xr[tid + 512];
    float s = v0 + v1 + v2;
    #pragma unroll
    for (int o = 32; o; o >>= 1) s += __shfl_down(s, o);
    if ((tid & 63) == 0) sb[0][tid >> 6] = s;
    __syncthreads();
    float mu = (sb[0][0] + sb[0][1] + sb[0][2] + sb[0][3]) * (1.f / DIM);
    float d0 = v0 - mu, d1 = v1 - mu, d2 = v2 - mu;
    float q = d0 * d0 + d1 * d1 + d2 * d2;
    #pragma unroll
    for (int o = 32; o; o >>= 1) q += __shfl_down(q, o);
    if ((tid & 63) == 0) sb[1][tid >> 6] = q;
    __syncthreads();
    float var = (sb[1][0] + sb[1][1] + sb[1][2] + sb[1][3]) * (1.f / DIM);
    float inv = rsqrtf(var + 1e-6f);
    short* yr = y + (size_t)row * DIM;
    yr[tid]       = f2bf(d0 * inv * g[tid]       + bta[tid]);
    yr[tid + 256] = f2bf(d1 * inv * g[tid + 256] + bta[tid + 256]);
    yr[tid + 512] = f2bf(d2 * inv * g[tid + 512] + bta[tid + 512]);
}

// ---------------------------------------------------------------------------
// GEMM: C[M,N] = A[M,K] @ W[N,K]^T (+bias, epilogue per MODE), bf16 inputs.
// BM=128, BN template (128/64). Per barrier-pair, TWO BK=32 panels are
// staged via global_load_lds(16B) into unpadded pitch-32 LDS (m97 layout),
// halving barrier count vs one-panel. 256 threads = 4 waves.
//   MODE 0: fp32 out = val + resid
//   MODE 2: bf16 out = gelu(val)
//   MODE 3: qkv — bn<1536: Q(*QSCALE)/K bf16; bn>=1536 (pure V):
//           LDS-transposed coalesced stores into vt[b,h,d,seq] (reuses the
//           A-panels' LDS after the K-loop).
// ---------------------------------------------------------------------------
template<int BN, int WM, int WN, int TM, int TN, int MODE>
__global__ __launch_bounds__(256) void gemm_bt(
    const short* __restrict__ A, const short* __restrict__ W,
    const float* __restrict__ bias, const float* __restrict__ resid,
    void* __restrict__ Cout, short* __restrict__ vt,
    int M, int N, int K)
{
    // carve: A0[128][32] | A1[128][32] | B0[BN][32] | B1[BN][32]
    __shared__ __align__(16) short smem[2 * 128 * 32 + 2 * BN * 32];
    short (*A0)[32] = (short(*)[32])smem;
    short (*A1)[32] = (short(*)[32])(smem + 128 * 32);
    short (*B0)[32] = (short(*)[32])(smem + 2 * 128 * 32);
    short (*B1)[32] = (short(*)[32])(smem + 2 * 128 * 32 + BN * 32);

    const int tid = threadIdx.x, lane = tid & 63, wv = tid >> 6;
    const int bm = blockIdx.y << 7;
    const int bn = blockIdx.x * BN;
    const int wmo = (wv / WN) * (TM * 16);
    const int wno = (wv % WN) * (TN * 16);
    const int l15 = lane & 15, quad = lane >> 4;

    const int srow = lane >> 2;            // 16 rows per wave-load
    const int scol = (lane & 3) << 3;      // 8-short (16B) chunk

    f32x4 acc[TM][TN] = {};

    for (int k0 = 0; k0 < K; k0 += 64) {
        __syncthreads();
        #pragma unroll
        for (int p = 0; p < 2; ++p) {
            const int rs = wv * 16 + p * 64;
            const short* ga = A + (size_t)(bm + rs + srow) * K + k0 + scol;
            gld_lds16(ga,      &A0[rs][0]);
            gld_lds16(ga + 32, &A1[rs][0]);
        }
        #pragma unroll
        for (int p = 0; p < BN / 64; ++p) {
            const int rs = wv * 16 + p * 64;
            const short* gw = W + (size_t)(bn + rs + srow) * K + k0 + scol;
            gld_lds16(gw,      &B0[rs][0]);
            gld_lds16(gw + 32, &B1[rs][0]);
        }
        __syncthreads();

        #pragma unroll
        for (int ks = 0; ks < 2; ++ks) {
            short (*As)[32] = ks ? A1 : A0;
            short (*Bs)[32] = ks ? B1 : B0;
            bf16x8 af[TM], bfr[TN];
            #pragma unroll
            for (int t = 0; t < TM; ++t)
                af[t] = *(const bf16x8*)&As[wmo + t * 16 + l15][quad << 3];
            #pragma unroll
            for (int u = 0; u < TN; ++u)
                bfr[u] = *(const bf16x8*)&Bs[wno + u * 16 + l15][quad << 3];
            #pragma unroll
            for (int t = 0; t < TM; ++t)
                #pragma unroll
                for (int u = 0; u < TN; ++u)
                    acc[t][u] = __builtin_amdgcn_mfma_f32_16x16x32_bf16(
                        af[t], bfr[u], acc[t][u], 0, 0, 0);
        }
    }

    if (MODE == 3 && bn >= 1536) {
        // ---- pure-V block: transpose via LDS (reuse A panels), coalesced ----
        short (*Tr)[136] = (short(*)[136])smem;   // 64 x 136 = 8704 <= 16384
        #pragma unroll 1
        for (int half = 0; half < 2; ++half) {
            __syncthreads();
            if ((wno >> 6) == half) {
                #pragma unroll
                for (int u = 0; u < TN; ++u) {
                    const float bv = bias[bn + half * 64 + u * 16 + l15];
                    #pragma unroll
                    for (int t = 0; t < TM; ++t)
                        *(short4*)&Tr[u * 16 + l15][wmo + t * 16 + (quad << 2)] =
                            pk4bf(acc[t][u][0] + bv, acc[t][u][1] + bv,
                                  acc[t][u][2] + bv, acc[t][u][3] + bv);
                }
            }
            __syncthreads();
            // cooperative store: 64 dd rows x 128 seq; 64B/thread contiguous
            const int dd = tid >> 2, seg = (tid & 3) << 5;   // 32 shorts
            const int col = bn + half * 64 + dd;
            const int hh = (col - 1536) >> 6, d = (col - 1536) & 63;
            const int b = bm >> 11, n0 = (bm & 2047) + seg;
            short* dst = &vt[((((size_t)b * NHEAD + hh) << 6) + d) * SEQ + n0];
            #pragma unroll
            for (int c = 0; c < 4; ++c)
                ((int4*)dst)[c] = *(const int4*)&Tr[dd][seg + (c << 3)];
        }
        return;
    }

    #pragma unroll
    for (int u = 0; u < TN; ++u) {
        const int col = bn + wno + u * 16 + l15;
        const float bv = bias[col];
        #pragma unroll
        for (int t = 0; t < TM; ++t) {
            const int row0 = bm + wmo + t * 16 + (quad << 2);
            #pragma unroll
            for (int r = 0; r < 4; ++r) {
                float v = acc[t][u][r] + bv;
                const size_t idx = (size_t)(row0 + r) * N + col;
                if (MODE == 0) {
                    ((float*)Cout)[idx] = v + resid[idx];
                } else if (MODE == 2) {
                    ((short*)Cout)[idx] = f2bf(gelu_f(v));
                } else {   // MODE 3, q/k region
                    if (col < DIM) v *= QSCALE;   // fold softmax scale+log2e
                    ((short*)Cout)[idx] = f2bf(v);
                }
            }
        }
    }
}

// ---------------------------------------------------------------------------
// Flash attention (transposed-S, shift-free softmax, K/V reg-prefetch).
// Grid (B*H, SEQ/128). 4 waves x 32 q-rows. Per 64-key block:
//   S^T = K*Q^T (lane = q-row) -> exp2 directly -> packed P stores ->
//   O^T += V^T*P. Next block's K/V global loads are issued right after the
//   staging barrier, consumed at the next iteration's ds_write (latency off
//   the critical path).
// ---------------------------------------------------------------------------
__global__ __launch_bounds__(256) void attn_k(
    const short* __restrict__ qkv, const short* __restrict__ vt,
    short* __restrict__ out)
{
    __shared__ __align__(16) short Ks[64][72];
    __shared__ __align__(16) short Vs[64][72];
    __shared__ __align__(16) short Ps[4][32][72];

    const int bh = blockIdx.x, b = bh / NHEAD, h = bh % NHEAD;
    const int qb = blockIdx.y;
    const int tid = threadIdx.x, lane = tid & 63, wv = tid >> 6;
    const int l15 = lane & 15, quad = lane >> 4;

    const size_t qbase = (size_t)b * SEQ * D3;
    const size_t vbase = (((size_t)bh) << 6) * SEQ;

    // Q fragments (used as MFMA B-operand: n=l15 -> q-row, k=quad*8+j -> d)
    bf16x8 qf[2][2];
    #pragma unroll
    for (int tm = 0; tm < 2; ++tm) {
        const int m = (qb << 7) + wv * 32 + tm * 16 + l15;
        #pragma unroll
        for (int ks = 0; ks < 2; ++ks)
            qf[tm][ks] = *(const bf16x8*)&qkv[qbase + (size_t)m * D3 + h * HDIM
                                             + ks * 32 + (quad << 3)];
    }

    float psum[2] = {0.f, 0.f};   // per-lane partial softmax denominators
    f32x4 acc[2][4] = {};         // O^T tiles: [q-tile][d-tile]

    const int srow = tid >> 3;            // 0..31
    const int scol = (tid & 7) << 3;      // 8-short chunk

    int4 kreg[2], vreg[2];
    #pragma unroll
    for (int p = 0; p < 2; ++p) {       // prefetch kb=0
        const int r = srow + p * 32;
        kreg[p] = *(const int4*)&qkv[qbase + (size_t)r * D3 + DIM + h * HDIM + scol];
        vreg[p] = *(const int4*)&vt[vbase + (size_t)r * SEQ + scol];
    }

    for (int kb = 0; kb < SEQ / 64; ++kb) {
        __syncthreads();
        #pragma unroll
        for (int p = 0; p < 2; ++p) {
            const int r = srow + p * 32;
            *(int4*)&Ks[r][scol] = kreg[p];
            *(int4*)&Vs[r][scol] = vreg[p];
        }
        __syncthreads();
        if (kb + 1 < SEQ / 64) {
            #pragma unroll
            for (int p = 0; p < 2; ++p) {
                const int r = srow + p * 32;
                kreg[p] = *(const int4*)&qkv[qbase
                    + (size_t)(((kb + 1) << 6) + r) * D3 + DIM + h * HDIM + scol];
                vreg[p] = *(const int4*)&vt[vbase
                    + (size_t)r * SEQ + ((kb + 1) << 6) + scol];
            }
        }

        // S^T = K Q^T : [key-tile kt][q-tile tm], lane col = q-row
        f32x4 st[2][4] = {};
        #pragma unroll
        for (int kt = 0; kt < 4; ++kt)
            #pragma unroll
            for (int ks = 0; ks < 2; ++ks) {
                bf16x8 kf = *(const bf16x8*)&Ks[kt * 16 + l15][ks * 32 + (quad << 3)];
                #pragma unroll
                for (int tm = 0; tm < 2; ++tm)
                    st[tm][kt] = __builtin_amdgcn_mfma_f32_16x16x32_bf16(
                        kf, qf[tm][ks], st[tm][kt], 0, 0, 0);
            }

        // shift-free softmax numerators: p = 2^s (s pre-scaled by QSCALE)
        #pragma unroll
        for (int tm = 0; tm < 2; ++tm) {
            #pragma unroll
            for (int kt = 0; kt < 4; ++kt) {
                const float p0 = exp2fast(st[tm][kt][0]);
                const float p1 = exp2fast(st[tm][kt][1]);
                const float p2 = exp2fast(st[tm][kt][2]);
                const float p3 = exp2fast(st[tm][kt][3]);
                psum[tm] += (p0 + p1) + (p2 + p3);
                *(short4*)&Ps[wv][tm * 16 + l15][kt * 16 + (quad << 2)] =
                    pk4bf(p0, p1, p2, p3);
            }
        }

        // O^T += V^T P : same-wave LDS roundtrip (DS ops in-order, no barrier)
        #pragma unroll
        for (int ks = 0; ks < 2; ++ks) {
            bf16x8 pf[2];
            #pragma unroll
            for (int tm = 0; tm < 2; ++tm)
                pf[tm] = *(const bf16x8*)&Ps[wv][tm * 16 + l15][ks * 32 + (quad << 3)];
            #pragma unroll
            for (int u = 0; u < 4; ++u) {
                bf16x8 vf = *(const bf16x8*)&Vs[u * 16 + l15][ks * 32 + (quad << 3)];
                #pragma unroll
                for (int tm = 0; tm < 2; ++tm)
                    acc[tm][u] = __builtin_amdgcn_mfma_f32_16x16x32_bf16(
                        vf, pf[tm], acc[tm][u], 0, 0, 0);
            }
        }
    }

    // reduce denominators across the 4 quads holding each q-row (once)
    #pragma unroll
    for (int tm = 0; tm < 2; ++tm) {
        psum[tm] += __shfl_xor(psum[tm], 16);
        psum[tm] += __shfl_xor(psum[tm], 32);
    }

    // O^T C-layout: lane q = l15, d = quad*4+r -> packed 8B stores
    #pragma unroll
    for (int tm = 0; tm < 2; ++tm) {
        const float inv = 1.f / psum[tm];
        const int q = (qb << 7) + wv * 32 + tm * 16 + l15;
        #pragma unroll
        for (int u = 0; u < 4; ++u) {
            const int d0 = u * 16 + (quad << 2);
            *(short4*)&out[((size_t)b * SEQ + q) * DIM + h * HDIM + d0] =
                pk4bf(acc[tm][u][0] * inv, acc[tm][u][1] * inv,
                      acc[tm][u][2] * inv, acc[tm][u][3] * inv);
        }
    }
}

// ---------------------------------------------------------------------------
extern "C" void kernel_launch(void* const* d_in, const int* in_sizes, int n_in,
                              void* d_out, int out_size, void* d_ws, size_t ws_size,
                              hipStream_t stream) {
    const float* x      = (const float*)d_in[0];
    const float* ln1_g  = (const float*)d_in[1];
    const float* ln1_b  = (const float*)d_in[2];
    const float* qkv_w  = (const float*)d_in[3];
    const float* qkv_b  = (const float*)d_in[4];
    const float* proj_w = (const float*)d_in[5];
    const float* proj_b = (const float*)d_in[6];
    const float* ln2_g  = (const float*)d_in[7];
    const float* ln2_b  = (const float*)d_in[8];
    const float* fc1_w  = (const float*)d_in[9];
    const float* fc1_b  = (const float*)d_in[10];
    const float* fc2_w  = (const float*)d_in[11];
    const float* fc2_b  = (const float*)d_in[12];
    float* out = (float*)d_out;

    // workspace (bf16 unless noted):
    //  wqkv|wproj|wfc1|wfc2 | h(LN1/attn-out) | big(qkv then f1) | vt(V^T/LN2) | x2 fp32
    short* ws16 = (short*)d_ws;
    short* wqkv = ws16;                         // 768*2304
    short* wprj = wqkv + (size_t)D3 * DIM;      // 768*768
    short* wf1  = wprj + (size_t)DIM * DIM;     // 3072*768
    short* wf2  = wf1  + (size_t)HID * DIM;     // 768*3072
    short* h    = wf2  + (size_t)DIM * HID;     // 8192*768
    short* big  = h    + (size_t)MTOT * DIM;    // 8192*3072 (qkv uses 8192*2304)
    short* vtb  = big  + (size_t)MTOT * HID;    // 48*64*2048
    float* x2   = (float*)(vtb + (size_t)MTOT * DIM);

    dim3 blk(256);

    // weights -> bf16 (one fused launch)
    const int n0 = (D3 * DIM) / 4, n1 = (DIM * DIM) / 4,
              n2 = (HID * DIM) / 4, n3 = (DIM * HID) / 4;
    tobf4_k<<<(n0 + n1 + n2 + n3 + 255) / 256, blk, 0, stream>>>(
        qkv_w, wqkv, n0, proj_w, wprj, n1, fc1_w, wf1, n2, fc2_w, wf2, n3);

    // 1) h = LN1(x)
    ln_k<<<MTOT, blk, 0, stream>>>(x, ln1_g, ln1_b, h);
    // 2) qkv = h @ qkv_w^T + b ; Q scaled; V part transposed into vtb
    gemm_bt<128, 2, 2, 4, 4, 3><<<dim3(D3 / 128, MTOT / 128), blk, 0, stream>>>(
        h, wqkv, qkv_b, nullptr, big, vtb, MTOT, D3, DIM);
    // 3) attn -> h
    attn_k<<<dim3(BATCH * NHEAD, SEQ / 128), blk, 0, stream>>>(big, vtb, h);
    // 4) x2 = x + attn @ proj_w^T + b
    gemm_bt<64, 4, 1, 2, 4, 0><<<dim3(DIM / 64, MTOT / 128), blk, 0, stream>>>(
        h, wprj, proj_b, x, x2, nullptr, MTOT, DIM, DIM);
    // 5) ln2 -> vtb
    ln_k<<<MTOT, blk, 0, stream>>>(x2, ln2_g, ln2_b, vtb);
    // 6) f1 = gelu(ln2 @ fc1_w^T + b) -> big
    gemm_bt<128, 2, 2, 4, 4, 2><<<dim3(HID / 128, MTOT / 128), blk, 0, stream>>>(
        vtb, wf1, fc1_b, nullptr, big, nullptr, MTOT, HID, DIM);
    // 7) out = x2 + f1 @ fc2_w^T + b
    gemm_bt<64, 4, 1, 2, 4, 0><<<dim3(DIM / 64, MTOT / 128), blk, 0, stream>>>(
        big, wf2, fc2_b, x2, out, nullptr, MTOT, DIM, HID);
}

// Round 9
// 429.986 us; speedup vs baseline: 1.0890x; 1.0890x over previous
//
#include <hip/hip_runtime.h>

// ---------------------------------------------------------------------------
// Transformer block, bf16-resident: LN1 -> QKV(+V-transpose) -> flash-MHA ->
// proj(+x) -> LN2 -> GELU-MLP(+x2).  B=4,N=2048,D=768,H=12,d=64,HID=3072.
// fp32 in/out; bf16 activations/weights; fp32 accum/softmax/residuals.
// GEMM: two BK=32 panels per barrier-pair (half the barrier drains).
// Attention: S^T=K*Q^T, O^T=V^T*P, shift-free softmax. (Round-8's K/V
// register-prefetch REVERTED: it caused scratch spills, WRITE 12->66 MB.)
// ---------------------------------------------------------------------------

#define DIM    768
#define NHEAD  12
#define HDIM   64
#define HID    3072
#define BATCH  4
#define SEQ    2048
#define MTOT   (BATCH * SEQ)      // 8192
#define D3     (3 * DIM)          // 2304

// 1/sqrt(64) * log2(e): folded into Q so softmax uses raw v_exp_f32 (2^x)
#define QSCALE 0.18033688011112042f
// 2*log2(e)*sqrt(2/pi) for exp2-based tanh-GELU
#define GELU_K 2.30220816f

typedef short bf16x8 __attribute__((ext_vector_type(8)));   // 4 VGPRs
typedef float f32x4  __attribute__((ext_vector_type(4)));

__device__ __forceinline__ float exp2fast(float x) {
    return __builtin_amdgcn_exp2f(x);      // v_exp_f32: 2^x
}

__device__ __forceinline__ float gelu_f(float v) {
    float y = v * (1.f + 0.044715f * v * v) * GELU_K;
    float t = exp2fast(fminf(y, 30.f));    // clamp: avoid inf/inf
#if __has_builtin(__builtin_amdgcn_rcpf)
    return v * t * __builtin_amdgcn_rcpf(t + 1.f);
#else
    return v * t / (t + 1.f);
#endif
}

__device__ __forceinline__ short f2bf(float f) {
    union { float f; unsigned u; } c; c.f = f;
    unsigned r = c.u + 0x7FFFu + ((c.u >> 16) & 1u);   // RNE
    return (short)(r >> 16);
}

// pack 4 fp32 -> 4 bf16 (hw pk-cvt when available)
__device__ __forceinline__ short4 pk4bf(float a, float b, float c, float d) {
#if __has_builtin(__builtin_amdgcn_cvt_pk_bf16_f32)
    auto lo = __builtin_amdgcn_cvt_pk_bf16_f32(a, b);
    auto hi = __builtin_amdgcn_cvt_pk_bf16_f32(c, d);
    union { decltype(lo) v; int i; } ul, uh;
    ul.v = lo; uh.v = hi;
    short4 r;
    *(int*)&r.x = ul.i; *(int*)&r.z = uh.i;
    return r;
#else
    return make_short4(f2bf(a), f2bf(b), f2bf(c), f2bf(d));
#endif
}

// async global->LDS, 16B per lane (wave-uniform LDS base, lane-scatter i*16)
__device__ __forceinline__ void gld_lds16(const short* g, short* l) {
    __builtin_amdgcn_global_load_lds(
        (const __attribute__((address_space(1))) unsigned int*)g,
        (__attribute__((address_space(3))) unsigned int*)l, 16, 0, 0);
}

// ---------------------------------------------------------------------------
// fp32 -> bf16 bulk convert, 4 weight tensors fused into one launch.
// ---------------------------------------------------------------------------
__global__ __launch_bounds__(256) void tobf4_k(
    const float* __restrict__ s0, short* __restrict__ d0, int n0,
    const float* __restrict__ s1, short* __restrict__ d1, int n1,
    const float* __restrict__ s2, short* __restrict__ d2, int n2,
    const float* __restrict__ s3, short* __restrict__ d3, int n3)
{
    int i = blockIdx.x * 256 + threadIdx.x;   // index in float4 units
    const float* s; short* d;
    if (i < n0)                { s = s0; d = d0; }
    else if ((i -= n0) < n1)   { s = s1; d = d1; }
    else if ((i -= n1) < n2)   { s = s2; d = d2; }
    else if ((i -= n2) < n3)   { s = s3; d = d3; }
    else return;
    float4 v = ((const float4*)s)[i];
    ((short4*)d)[i] = pk4bf(v.x, v.y, v.z, v.w);
}

// ---------------------------------------------------------------------------
// LayerNorm, fp32 in -> bf16 out. One 256-thread block per row of 768.
// ---------------------------------------------------------------------------
__global__ __launch_bounds__(256) void ln_k(
    const float* __restrict__ x, const float* __restrict__ g,
    const float* __restrict__ bta, short* __restrict__ y)
{
    __shared__ float sb[2][4];
    const int row = blockIdx.x, tid = threadIdx.x;
    const float* xr = x + (size_t)row * DIM;
    float v0 = xr[tid], v1 = xr[tid + 256], v2 = xr[tid + 512];
    float s = v0 + v1 + v2;
    #pragma unroll
    for (int o = 32; o; o >>= 1) s += __shfl_down(s, o);
    if ((tid & 63) == 0) sb[0][tid >> 6] = s;
    __syncthreads();
    float mu = (sb[0][0] + sb[0][1] + sb[0][2] + sb[0][3]) * (1.f / DIM);
    float d0 = v0 - mu, d1 = v1 - mu, d2 = v2 - mu;
    float q = d0 * d0 + d1 * d1 + d2 * d2;
    #pragma unroll
    for (int o = 32; o; o >>= 1) q += __shfl_down(q, o);
    if ((tid & 63) == 0) sb[1][tid >> 6] = q;
    __syncthreads();
    float var = (sb[1][0] + sb[1][1] + sb[1][2] + sb[1][3]) * (1.f / DIM);
    float inv = rsqrtf(var + 1e-6f);
    short* yr = y + (size_t)row * DIM;
    yr[tid]       = f2bf(d0 * inv * g[tid]       + bta[tid]);
    yr[tid + 256] = f2bf(d1 * inv * g[tid + 256] + bta[tid + 256]);
    yr[tid + 512] = f2bf(d2 * inv * g[tid + 512] + bta[tid + 512]);
}

// ---------------------------------------------------------------------------
// GEMM: C[M,N] = A[M,K] @ W[N,K]^T (+bias, epilogue per MODE), bf16 inputs.
// BM=128, BN template (128/64). Per barrier-pair, TWO BK=32 panels are
// staged via global_load_lds(16B) into unpadded pitch-32 LDS (m97 layout),
// halving barrier count vs one-panel. 256 threads = 4 waves.
//   MODE 0: fp32 out = val + resid
//   MODE 2: bf16 out = gelu(val)
//   MODE 3: qkv — bn<1536: Q(*QSCALE)/K bf16; bn>=1536 (pure V):
//           LDS-transposed coalesced stores into vt[b,h,d,seq].
// ---------------------------------------------------------------------------
template<int BN, int WM, int WN, int TM, int TN, int MODE>
__global__ __launch_bounds__(256) void gemm_bt(
    const short* __restrict__ A, const short* __restrict__ W,
    const float* __restrict__ bias, const float* __restrict__ resid,
    void* __restrict__ Cout, short* __restrict__ vt,
    int M, int N, int K)
{
    // carve: A0[128][32] | A1[128][32] | B0[BN][32] | B1[BN][32]
    __shared__ __align__(16) short smem[2 * 128 * 32 + 2 * BN * 32];
    short (*A0)[32] = (short(*)[32])smem;
    short (*A1)[32] = (short(*)[32])(smem + 128 * 32);
    short (*B0)[32] = (short(*)[32])(smem + 2 * 128 * 32);
    short (*B1)[32] = (short(*)[32])(smem + 2 * 128 * 32 + BN * 32);

    const int tid = threadIdx.x, lane = tid & 63, wv = tid >> 6;
    const int bm = blockIdx.y << 7;
    const int bn = blockIdx.x * BN;
    const int wmo = (wv / WN) * (TM * 16);
    const int wno = (wv % WN) * (TN * 16);
    const int l15 = lane & 15, quad = lane >> 4;

    const int srow = lane >> 2;            // 16 rows per wave-load
    const int scol = (lane & 3) << 3;      // 8-short (16B) chunk

    f32x4 acc[TM][TN] = {};

    for (int k0 = 0; k0 < K; k0 += 64) {
        __syncthreads();
        #pragma unroll
        for (int p = 0; p < 2; ++p) {
            const int rs = wv * 16 + p * 64;
            const short* ga = A + (size_t)(bm + rs + srow) * K + k0 + scol;
            gld_lds16(ga,      &A0[rs][0]);
            gld_lds16(ga + 32, &A1[rs][0]);
        }
        #pragma unroll
        for (int p = 0; p < BN / 64; ++p) {
            const int rs = wv * 16 + p * 64;
            const short* gw = W + (size_t)(bn + rs + srow) * K + k0 + scol;
            gld_lds16(gw,      &B0[rs][0]);
            gld_lds16(gw + 32, &B1[rs][0]);
        }
        __syncthreads();

        #pragma unroll
        for (int ks = 0; ks < 2; ++ks) {
            short (*As)[32] = ks ? A1 : A0;
            short (*Bs)[32] = ks ? B1 : B0;
            bf16x8 af[TM], bfr[TN];
            #pragma unroll
            for (int t = 0; t < TM; ++t)
                af[t] = *(const bf16x8*)&As[wmo + t * 16 + l15][quad << 3];
            #pragma unroll
            for (int u = 0; u < TN; ++u)
                bfr[u] = *(const bf16x8*)&Bs[wno + u * 16 + l15][quad << 3];
            #pragma unroll
            for (int t = 0; t < TM; ++t)
                #pragma unroll
                for (int u = 0; u < TN; ++u)
                    acc[t][u] = __builtin_amdgcn_mfma_f32_16x16x32_bf16(
                        af[t], bfr[u], acc[t][u], 0, 0, 0);
        }
    }

    if (MODE == 3 && bn >= 1536) {
        // ---- pure-V block: transpose via LDS (reuse A panels), coalesced ----
        short (*Tr)[136] = (short(*)[136])smem;   // 64 x 136 = 8704 <= 16384
        #pragma unroll 1
        for (int half = 0; half < 2; ++half) {
            __syncthreads();
            if ((wno >> 6) == half) {
                #pragma unroll
                for (int u = 0; u < TN; ++u) {
                    const float bv = bias[bn + half * 64 + u * 16 + l15];
                    #pragma unroll
                    for (int t = 0; t < TM; ++t)
                        *(short4*)&Tr[u * 16 + l15][wmo + t * 16 + (quad << 2)] =
                            pk4bf(acc[t][u][0] + bv, acc[t][u][1] + bv,
                                  acc[t][u][2] + bv, acc[t][u][3] + bv);
                }
            }
            __syncthreads();
            // cooperative store: 64 dd rows x 128 seq; 64B/thread contiguous
            const int dd = tid >> 2, seg = (tid & 3) << 5;   // 32 shorts
            const int col = bn + half * 64 + dd;
            const int hh = (col - 1536) >> 6, d = (col - 1536) & 63;
            const int b = bm >> 11, n0 = (bm & 2047) + seg;
            short* dst = &vt[((((size_t)b * NHEAD + hh) << 6) + d) * SEQ + n0];
            #pragma unroll
            for (int c = 0; c < 4; ++c)
                ((int4*)dst)[c] = *(const int4*)&Tr[dd][seg + (c << 3)];
        }
        return;
    }

    #pragma unroll
    for (int u = 0; u < TN; ++u) {
        const int col = bn + wno + u * 16 + l15;
        const float bv = bias[col];
        #pragma unroll
        for (int t = 0; t < TM; ++t) {
            const int row0 = bm + wmo + t * 16 + (quad << 2);
            #pragma unroll
            for (int r = 0; r < 4; ++r) {
                float v = acc[t][u][r] + bv;
                const size_t idx = (size_t)(row0 + r) * N + col;
                if (MODE == 0) {
                    ((float*)Cout)[idx] = v + resid[idx];
                } else if (MODE == 2) {
                    ((short*)Cout)[idx] = f2bf(gelu_f(v));
                } else {   // MODE 3, q/k region
                    if (col < DIM) v *= QSCALE;   // fold softmax scale+log2e
                    ((short*)Cout)[idx] = f2bf(v);
                }
            }
        }
    }
}

// ---------------------------------------------------------------------------
// Flash attention (transposed-S, shift-free softmax), bf16 in/out.
// Grid (B*H, SEQ/128). 4 waves x 32 q-rows. Per 64-key block:
//   S^T = K*Q^T (lane = q-row) -> exp2 directly (no max, no rescale) ->
//   packed P stores -> O^T += V^T*P. Per-lane partial sums; one cross-lane
//   reduction at the end.  (Round-7 version: direct int4 staging, no
//   register prefetch.)
// ---------------------------------------------------------------------------
__global__ __launch_bounds__(256) void attn_k(
    const short* __restrict__ qkv, const short* __restrict__ vt,
    short* __restrict__ out)
{
    __shared__ __align__(16) short Ks[64][72];
    __shared__ __align__(16) short Vs[64][72];
    __shared__ __align__(16) short Ps[4][32][72];

    const int bh = blockIdx.x, b = bh / NHEAD, h = bh % NHEAD;
    const int qb = blockIdx.y;
    const int tid = threadIdx.x, lane = tid & 63, wv = tid >> 6;
    const int l15 = lane & 15, quad = lane >> 4;

    const size_t qbase = (size_t)b * SEQ * D3;
    const size_t vbase = (((size_t)bh) << 6) * SEQ;

    // Q fragments (used as MFMA B-operand: n=l15 -> q-row, k=quad*8+j -> d)
    bf16x8 qf[2][2];
    #pragma unroll
    for (int tm = 0; tm < 2; ++tm) {
        const int m = (qb << 7) + wv * 32 + tm * 16 + l15;
        #pragma unroll
        for (int ks = 0; ks < 2; ++ks)
            qf[tm][ks] = *(const bf16x8*)&qkv[qbase + (size_t)m * D3 + h * HDIM
                                             + ks * 32 + (quad << 3)];
    }

    float psum[2] = {0.f, 0.f};   // per-lane partial softmax denominators
    f32x4 acc[2][4] = {};         // O^T tiles: [q-tile][d-tile]

    const int srow = tid >> 3;            // 0..31
    const int scol = (tid & 7) << 3;      // 8-short chunk

    for (int kb = 0; kb < SEQ / 64; ++kb) {
        __syncthreads();
        #pragma unroll
        for (int p = 0; p < 2; ++p) {
            const int r = srow + p * 32;
            *(int4*)&Ks[r][scol] = *(const int4*)&qkv[qbase
                + (size_t)((kb << 6) + r) * D3 + DIM + h * HDIM + scol];
            *(int4*)&Vs[r][scol] = *(const int4*)&vt[vbase
                + (size_t)r * SEQ + (kb << 6) + scol];
        }
        __syncthreads();

        // S^T = K Q^T : [key-tile kt][q-tile tm], lane col = q-row
        f32x4 st[2][4] = {};
        #pragma unroll
        for (int kt = 0; kt < 4; ++kt)
            #pragma unroll
            for (int ks = 0; ks < 2; ++ks) {
                bf16x8 kf = *(const bf16x8*)&Ks[kt * 16 + l15][ks * 32 + (quad << 3)];
                #pragma unroll
                for (int tm = 0; tm < 2; ++tm)
                    st[tm][kt] = __builtin_amdgcn_mfma_f32_16x16x32_bf16(
                        kf, qf[tm][ks], st[tm][kt], 0, 0, 0);
            }

        // shift-free softmax numerators: p = 2^s (s pre-scaled by QSCALE)
        #pragma unroll
        for (int tm = 0; tm < 2; ++tm) {
            #pragma unroll
            for (int kt = 0; kt < 4; ++kt) {
                const float p0 = exp2fast(st[tm][kt][0]);
                const float p1 = exp2fast(st[tm][kt][1]);
                const float p2 = exp2fast(st[tm][kt][2]);
                const float p3 = exp2fast(st[tm][kt][3]);
                psum[tm] += (p0 + p1) + (p2 + p3);
                *(short4*)&Ps[wv][tm * 16 + l15][kt * 16 + (quad << 2)] =
                    pk4bf(p0, p1, p2, p3);
            }
        }

        // O^T += V^T P : same-wave LDS roundtrip (DS ops in-order, no barrier)
        #pragma unroll
        for (int ks = 0; ks < 2; ++ks) {
            bf16x8 pf[2];
            #pragma unroll
            for (int tm = 0; tm < 2; ++tm)
                pf[tm] = *(const bf16x8*)&Ps[wv][tm * 16 + l15][ks * 32 + (quad << 3)];
            #pragma unroll
            for (int u = 0; u < 4; ++u) {
                bf16x8 vf = *(const bf16x8*)&Vs[u * 16 + l15][ks * 32 + (quad << 3)];
                #pragma unroll
                for (int tm = 0; tm < 2; ++tm)
                    acc[tm][u] = __builtin_amdgcn_mfma_f32_16x16x32_bf16(
                        vf, pf[tm], acc[tm][u], 0, 0, 0);
            }
        }
    }

    // reduce denominators across the 4 quads holding each q-row (once)
    #pragma unroll
    for (int tm = 0; tm < 2; ++tm) {
        psum[tm] += __shfl_xor(psum[tm], 16);
        psum[tm] += __shfl_xor(psum[tm], 32);
    }

    // O^T C-layout: lane q = l15, d = quad*4+r -> packed 8B stores
    #pragma unroll
    for (int tm = 0; tm < 2; ++tm) {
        const float inv = 1.f / psum[tm];
        const int q = (qb << 7) + wv * 32 + tm * 16 + l15;
        #pragma unroll
        for (int u = 0; u < 4; ++u) {
            const int d0 = u * 16 + (quad << 2);
            *(short4*)&out[((size_t)b * SEQ + q) * DIM + h * HDIM + d0] =
                pk4bf(acc[tm][u][0] * inv, acc[tm][u][1] * inv,
                      acc[tm][u][2] * inv, acc[tm][u][3] * inv);
        }
    }
}

// ---------------------------------------------------------------------------
extern "C" void kernel_launch(void* const* d_in, const int* in_sizes, int n_in,
                              void* d_out, int out_size, void* d_ws, size_t ws_size,
                              hipStream_t stream) {
    const float* x      = (const float*)d_in[0];
    const float* ln1_g  = (const float*)d_in[1];
    const float* ln1_b  = (const float*)d_in[2];
    const float* qkv_w  = (const float*)d_in[3];
    const float* qkv_b  = (const float*)d_in[4];
    const float* proj_w = (const float*)d_in[5];
    const float* proj_b = (const float*)d_in[6];
    const float* ln2_g  = (const float*)d_in[7];
    const float* ln2_b  = (const float*)d_in[8];
    const float* fc1_w  = (const float*)d_in[9];
    const float* fc1_b  = (const float*)d_in[10];
    const float* fc2_w  = (const float*)d_in[11];
    const float* fc2_b  = (const float*)d_in[12];
    float* out = (float*)d_out;

    // workspace (bf16 unless noted):
    //  wqkv|wproj|wfc1|wfc2 | h(LN1/attn-out) | big(qkv then f1) | vt(V^T/LN2) | x2 fp32
    short* ws16 = (short*)d_ws;
    short* wqkv = ws16;                         // 768*2304
    short* wprj = wqkv + (size_t)D3 * DIM;      // 768*768
    short* wf1  = wprj + (size_t)DIM * DIM;     // 3072*768
    short* wf2  = wf1  + (size_t)HID * DIM;     // 768*3072
    short* h    = wf2  + (size_t)DIM * HID;     // 8192*768
    short* big  = h    + (size_t)MTOT * DIM;    // 8192*3072 (qkv uses 8192*2304)
    short* vtb  = big  + (size_t)MTOT * HID;    // 48*64*2048
    float* x2   = (float*)(vtb + (size_t)MTOT * DIM);

    dim3 blk(256);

    // weights -> bf16 (one fused launch)
    const int n0 = (D3 * DIM) / 4, n1 = (DIM * DIM) / 4,
              n2 = (HID * DIM) / 4, n3 = (DIM * HID) / 4;
    tobf4_k<<<(n0 + n1 + n2 + n3 + 255) / 256, blk, 0, stream>>>(
        qkv_w, wqkv, n0, proj_w, wprj, n1, fc1_w, wf1, n2, fc2_w, wf2, n3);

    // 1) h = LN1(x)
    ln_k<<<MTOT, blk, 0, stream>>>(x, ln1_g, ln1_b, h);
    // 2) qkv = h @ qkv_w^T + b ; Q scaled; V part transposed into vtb
    gemm_bt<128, 2, 2, 4, 4, 3><<<dim3(D3 / 128, MTOT / 128), blk, 0, stream>>>(
        h, wqkv, qkv_b, nullptr, big, vtb, MTOT, D3, DIM);
    // 3) attn -> h
    attn_k<<<dim3(BATCH * NHEAD, SEQ / 128), blk, 0, stream>>>(big, vtb, h);
    // 4) x2 = x + attn @ proj_w^T + b
    gemm_bt<64, 4, 1, 2, 4, 0><<<dim3(DIM / 64, MTOT / 128), blk, 0, stream>>>(
        h, wprj, proj_b, x, x2, nullptr, MTOT, DIM, DIM);
    // 5) ln2 -> vtb
    ln_k<<<MTOT, blk, 0, stream>>>(x2, ln2_g, ln2_b, vtb);
    // 6) f1 = gelu(ln2 @ fc1_w^T + b) -> big
    gemm_bt<128, 2, 2, 4, 4, 2><<<dim3(HID / 128, MTOT / 128), blk, 0, stream>>>(
        vtb, wf1, fc1_b, nullptr, big, nullptr, MTOT, HID, DIM);
    // 7) out = x2 + f1 @ fc2_w^T + b
    gemm_bt<64, 4, 1, 2, 4, 0><<<dim3(DIM / 64, MTOT / 128), blk, 0, stream>>>(
        big, wf2, fc2_b, x2, out, nullptr, MTOT, DIM, HID);
}